// Round 6
// baseline (1119.079 us; speedup 1.0000x reference)
//
#include <hip/hip_runtime.h>
#include <hip/hip_bf16.h>
#include <math.h>

typedef __attribute__((ext_vector_type(8))) short bf16x8;
typedef __attribute__((ext_vector_type(4))) float f32x4;
typedef __hip_bfloat16 bf16;

__device__ __forceinline__ void gload_lds16(const void* g, void* l) {
  __builtin_amdgcn_global_load_lds((const __attribute__((address_space(1))) void*)g,
                                   (__attribute__((address_space(3))) void*)l,
                                   16, 0, 0);
}

__device__ __forceinline__ float gelu_erf(float x) {
  return 0.5f * x * (1.0f + erff(x * 0.70710678118654752f));
}

// ---------------- convert f32 -> bf16 (vectorized) ----------------
__global__ __launch_bounds__(256) void k_cvt_bf16(const float* __restrict__ in,
                                                  bf16* __restrict__ out, int n4) {
  int i = blockIdx.x * 256 + threadIdx.x;
  const int stride = gridDim.x * 256;
  for (; i < n4; i += stride) {
    float4 v = reinterpret_cast<const float4*>(in)[i];
    bf16* o = out + (size_t)i * 4;
    o[0] = __float2bfloat16(v.x);
    o[1] = __float2bfloat16(v.y);
    o[2] = __float2bfloat16(v.z);
    o[3] = __float2bfloat16(v.w);
  }
}

// ---------------- transpose f32 [R][C] -> bf16 [C][R] ----------------
__global__ __launch_bounds__(256) void k_transpose_w(const float* __restrict__ in,
                                                     bf16* __restrict__ out,
                                                     int R, int C) {
  __shared__ float tile[32][33];
  const int c0 = blockIdx.x * 32, r0 = blockIdx.y * 32;
  const int tx = threadIdx.x & 31, ty = threadIdx.x >> 5;
  for (int i = 0; i < 32; i += 8)
    tile[ty + i][tx] = in[(size_t)(r0 + ty + i) * C + c0 + tx];
  __syncthreads();
  for (int i = 0; i < 32; i += 8)
    out[(size_t)(c0 + ty + i) * R + r0 + tx] = __float2bfloat16(tile[tx][ty + i]);
}

// ------------- per-head V transpose: [B*S][E] -> [(b*H+h)*128 + d][S] -------------
__global__ __launch_bounds__(256) void k_transpose_v(const bf16* __restrict__ Vb,
                                                     bf16* __restrict__ Vt) {
  __shared__ bf16 tile[32][34];
  const int bh = blockIdx.z;
  const int b = bh >> 3, h = bh & 7;
  const int s0 = blockIdx.x * 32, d0 = blockIdx.y * 32;
  const int tx = threadIdx.x & 31, ty = threadIdx.x >> 5;
  for (int i = 0; i < 32; i += 8)
    tile[ty + i][tx] = Vb[((size_t)b * 512 + s0 + ty + i) * 1024 + h * 128 + d0 + tx];
  __syncthreads();
  for (int i = 0; i < 32; i += 8)
    Vt[((size_t)bh * 128 + d0 + ty + i) * 512 + s0 + tx] = tile[tx][ty + i];
}

// ======== 256x256 tile, K_STEP=32, 4-slot LDS, counted-vmcnt pipelined GEMM ========
// C[M][N] = A[M][K] * Bt[N][K]^T + bias. EPI: 0=bf16, 1=gelu->bf16, 2=f32(+=ACC)
// LDS 128KB = 4 slots x (A[256 rows][32k] 16KB + B[256][32k] 16KB). Rows = 64B.
// Swizzle: 16B-slot' = slot ^ ((row>>1)&3) (involution; granule-uniform read);
// applied as inverse-swizzled GLOBAL source (gload_lds dest linear) + swizzled ds_read.
// Pipeline: prefetch depth 3; vmcnt(12) in steady state (4 loads/thread/step x 3 steps
// in flight, NEVER 0 in main loop); tail peels 8/4/0. Each wave issues exactly 4
// loads/step, so own-wave vmcnt + s_barrier => whole slot visible. Requires K>=128.
template <int EPI, bool ACC>
__global__ __launch_bounds__(512, 2) void k_gemm256(
    const bf16* __restrict__ A, const bf16* __restrict__ Bt,
    const float* __restrict__ bias, void* __restrict__ Cout,
    int K, int lda, int ldb, int ldc) {
  __shared__ __attribute__((aligned(16))) char lds[131072];
  const int t = threadIdx.x, w = t >> 6, l = t & 63;
  const int gx = gridDim.x, nwg = gx * gridDim.y;
  int bid = blockIdx.y * gx + blockIdx.x;
  bid = (bid & 7) * (nwg >> 3) + (bid >> 3);  // XCD swizzle (nwg % 8 == 0)
  const int bm = bid / gx, bn = bid % gx;
  const int wm = w >> 2, wn = w & 3;  // 2M x 4N waves, per-wave C = 128x64
  const int lq = l >> 4, lr = l & 15;

  // ---- staging source pointers (inverse-swizzled global; LDS dest linear) ----
  const int srow = t >> 2;                                   // rows 0..127 (round0)
  const int sslot = (t & 3) ^ ((srow >> 1) & 3);             // src 16B slot in 64B seg
  const size_t ldab = (size_t)lda * 2, ldbb = (size_t)ldb * 2;
  const char* pA0 = (const char*)(A + (size_t)(bm * 256) * lda) + (size_t)srow * ldab + sslot * 16;
  const char* pA1 = pA0 + 128 * ldab;                        // rows 128..255 (same swz)
  const char* pB0 = (const char*)(Bt + (size_t)(bn * 256) * ldb) + (size_t)srow * ldbb + sslot * 16;
  const char* pB1 = pB0 + 128 * ldbb;
  char* const ldst = lds + w * 1024;                         // wave-uniform (+lane*16 HW)

  // ---- fragment read offsets (swizzled; swz independent of fr/fc/wm/wn) ----
  const int swz = (lq ^ ((lr >> 1) & 3)) << 4;
  const int aoffb = wm * 8192 + lr * 64 + swz;               // + fr*1024
  const int boffb = 16384 + wn * 4096 + lr * 64 + swz;       // + fc*1024

  f32x4 acc[8][4];
#pragma unroll
  for (int m = 0; m < 8; ++m)
#pragma unroll
    for (int n = 0; n < 4; ++n) acc[m][n] = (f32x4){0.f, 0.f, 0.f, 0.f};

  const int NT = K >> 5;  // K_STEP=32

#define ISSUE(s)                                                        \
  {                                                                     \
    char* dst = ldst + ((s) & 3) * 32768;                               \
    gload_lds16(pA0, dst);                                              \
    gload_lds16(pA1, dst + 8192);                                       \
    gload_lds16(pB0, dst + 16384);                                      \
    gload_lds16(pB1, dst + 24576);                                      \
    pA0 += 64; pA1 += 64; pB0 += 64; pB1 += 64;                         \
  }

#define COMPUTE(s)                                                      \
  {                                                                     \
    const char* Ab = lds + ((s) & 3) * 32768 + aoffb;                   \
    const char* Bb = lds + ((s) & 3) * 32768 + boffb;                   \
    bf16x8 aF[8], bF[4];                                                \
    _Pragma("unroll") for (int fr = 0; fr < 8; ++fr)                    \
        aF[fr] = *(const bf16x8*)(Ab + fr * 1024);                      \
    _Pragma("unroll") for (int fc = 0; fc < 4; ++fc)                    \
        bF[fc] = *(const bf16x8*)(Bb + fc * 1024);                      \
    __builtin_amdgcn_s_setprio(1);                                      \
    _Pragma("unroll") for (int fr = 0; fr < 8; ++fr)                    \
        _Pragma("unroll") for (int fc = 0; fc < 4; ++fc)                \
            acc[fr][fc] = __builtin_amdgcn_mfma_f32_16x16x32_bf16(      \
                aF[fr], bF[fc], acc[fr][fc], 0, 0, 0);                  \
    __builtin_amdgcn_s_setprio(0);                                      \
  }

  // prologue: steps 0..2 in flight (12 loads/thread)
  ISSUE(0); ISSUE(1); ISSUE(2);

  for (int s = 0; s < NT; ++s) {
    if (s + 3 < NT) {
      ISSUE(s + 3);
      asm volatile("s_waitcnt vmcnt(12)" ::: "memory");  // step s landed, 3 in flight
    } else if (s + 3 == NT) {
      asm volatile("s_waitcnt vmcnt(8)" ::: "memory");
    } else if (s + 2 == NT) {
      asm volatile("s_waitcnt vmcnt(4)" ::: "memory");
    } else {
      asm volatile("s_waitcnt vmcnt(0)" ::: "memory");
    }
    __builtin_amdgcn_s_barrier();   // all waves' step-s loads visible
    COMPUTE(s);
    __builtin_amdgcn_s_barrier();   // slot (s&3) free for ISSUE(s+4)
  }
#undef ISSUE
#undef COMPUTE

  // ---- epilogue ----
  const int rowb = bm * 256 + wm * 128;
  const int colb = bn * 256 + wn * 64;
#pragma unroll
  for (int fr = 0; fr < 8; ++fr) {
#pragma unroll
    for (int fc = 0; fc < 4; ++fc) {
      const int col = colb + fc * 16 + lr;
      const float bv = bias ? bias[col] : 0.0f;
#pragma unroll
      for (int i = 0; i < 4; ++i) {
        const int row = rowb + fr * 16 + lq * 4 + i;
        float v = acc[fr][fc][i] + bv;
        if (EPI == 1) v = gelu_erf(v);
        if (EPI <= 1) {
          ((bf16*)Cout)[(size_t)row * ldc + col] = __float2bfloat16(v);
        } else {
          float* Cf = (float*)Cout;
          const size_t idx = (size_t)row * ldc + col;
          if (ACC) v += Cf[idx];
          Cf[idx] = v;
        }
      }
    }
  }
}

// ---------------- attention v3 (unchanged this round; LDS-staged rework next) ----------------
__global__ __launch_bounds__(256) void k_attn(const bf16* __restrict__ Qg,
                                              const bf16* __restrict__ Kg,
                                              const bf16* __restrict__ Vt,
                                              bf16* __restrict__ Og) {
  __shared__ bf16 Pl[32][520];
  __shared__ float redm[2][32];
  __shared__ float reds[2][32];
  int bid = blockIdx.y * 16 + blockIdx.x;
  bid = (bid & 7) * (4096 >> 3) + (bid >> 3);
  const int bh = bid / 16, q0 = (bid % 16) * 32;
  const int b = bh >> 3, h = bh & 7;
  const int t = threadIdx.x, w = t >> 6, l = t & 63;
  const int lq = l >> 4, lr = l & 15;
  const int rt = w & 1, ch = w >> 1;
  const int myrow = rt * 16 + lq * 4;

  const bf16* qbase = Qg + ((size_t)b * 512 + q0 + rt * 16 + lr) * 1024 + h * 128;
  bf16x8 afr[4];
#pragma unroll
  for (int d0 = 0; d0 < 4; ++d0)
    afr[d0] = *(const bf16x8*)(qbase + d0 * 32 + lq * 8);

  const bf16* kb2 = Kg + (size_t)b * 512 * 1024 + h * 128 +
                    (size_t)(ch * 256 + lr) * 1024 + lq * 8;
  f32x4 sc[16];
  bf16x8 K0[4], K1[4], K2[4], K3[4];

#define LOADK(BUF, CT)                                                   \
  {                                                                      \
    _Pragma("unroll") for (int d0 = 0; d0 < 4; ++d0)                     \
        BUF[d0] = *(const bf16x8*)(kb2 + (CT)*16384 + d0 * 32);          \
  }
#define QKT(CT, BUF)                                                     \
  {                                                                      \
    f32x4 a = (f32x4){0.f, 0.f, 0.f, 0.f};                               \
    _Pragma("unroll") for (int d0 = 0; d0 < 4; ++d0)                     \
        a = __builtin_amdgcn_mfma_f32_16x16x32_bf16(afr[d0], BUF[d0], a, 0, 0, 0); \
    sc[CT] = a;                                                          \
  }

  LOADK(K0, 0) LOADK(K1, 1) LOADK(K2, 2) LOADK(K3, 3)
  QKT(0, K0)  LOADK(K0, 4)
  QKT(1, K1)  LOADK(K1, 5)
  QKT(2, K2)  LOADK(K2, 6)
  QKT(3, K3)  LOADK(K3, 7)
  QKT(4, K0)  LOADK(K0, 8)
  QKT(5, K1)  LOADK(K1, 9)
  QKT(6, K2)  LOADK(K2, 10)
  QKT(7, K3)  LOADK(K3, 11)
  QKT(8, K0)  LOADK(K0, 12)
  QKT(9, K1)  LOADK(K1, 13)
  QKT(10, K2) LOADK(K2, 14)
  QKT(11, K3) LOADK(K3, 15)
  QKT(12, K0) QKT(13, K1) QKT(14, K2) QKT(15, K3)
#undef LOADK
#undef QKT

  float m4[4];
#pragma unroll
  for (int i = 0; i < 4; ++i) {
    float m = sc[0][i];
#pragma unroll
    for (int ct = 1; ct < 16; ++ct) m = fmaxf(m, sc[ct][i]);
    m4[i] = m;
  }
#pragma unroll
  for (int i = 0; i < 4; ++i) {
    m4[i] = fmaxf(m4[i], __shfl_xor(m4[i], 1));
    m4[i] = fmaxf(m4[i], __shfl_xor(m4[i], 2));
    m4[i] = fmaxf(m4[i], __shfl_xor(m4[i], 4));
    m4[i] = fmaxf(m4[i], __shfl_xor(m4[i], 8));
  }
  if (lr == 0) {
#pragma unroll
    for (int i = 0; i < 4; ++i) redm[ch][myrow + i] = m4[i];
  }
  __syncthreads();
  float fm[4];
#pragma unroll
  for (int i = 0; i < 4; ++i)
    fm[i] = fmaxf(redm[0][myrow + i], redm[1][myrow + i]);

  float s4[4] = {0.f, 0.f, 0.f, 0.f};
#pragma unroll
  for (int ct = 0; ct < 16; ++ct) {
    const int col = ch * 256 + ct * 16 + lr;
#pragma unroll
    for (int i = 0; i < 4; ++i) {
      const float e = __expf(sc[ct][i] - fm[i]);
      s4[i] += e;
      Pl[myrow + i][col] = __float2bfloat16(e);
    }
  }
#pragma unroll
  for (int i = 0; i < 4; ++i) {
    s4[i] += __shfl_xor(s4[i], 1);
    s4[i] += __shfl_xor(s4[i], 2);
    s4[i] += __shfl_xor(s4[i], 4);
    s4[i] += __shfl_xor(s4[i], 8);
  }
  if (lr == 0) {
#pragma unroll
    for (int i = 0; i < 4; ++i) reds[ch][myrow + i] = s4[i];
  }
  __syncthreads();

  const bf16* vb2 = Vt + (size_t)bh * 128 * 512 +
                    (size_t)(ch * 64 + lr) * 512 + lq * 8;
  f32x4 oacc[4];
#pragma unroll
  for (int n = 0; n < 4; ++n) oacc[n] = (f32x4){0.f, 0.f, 0.f, 0.f};
  bf16x8 V0[4], V1[4], V2[4], V3[4];

#define LOADV(BUF, IT)                                                   \
  {                                                                      \
    _Pragma("unroll") for (int n = 0; n < 4; ++n)                        \
        BUF[n] = *(const bf16x8*)(vb2 + (size_t)n * 16 * 512 + (IT)*32); \
  }
#define PVM(IT, BUF)                                                     \
  {                                                                      \
    bf16x8 pa = *(const bf16x8*)&Pl[rt * 16 + lr][(IT)*32 + lq * 8];     \
    _Pragma("unroll") for (int n = 0; n < 4; ++n)                        \
        oacc[n] = __builtin_amdgcn_mfma_f32_16x16x32_bf16(pa, BUF[n], oacc[n], 0, 0, 0); \
  }

  LOADV(V0, 0) LOADV(V1, 1) LOADV(V2, 2) LOADV(V3, 3)
  PVM(0, V0)  LOADV(V0, 4)
  PVM(1, V1)  LOADV(V1, 5)
  PVM(2, V2)  LOADV(V2, 6)
  PVM(3, V3)  LOADV(V3, 7)
  PVM(4, V0)  LOADV(V0, 8)
  PVM(5, V1)  LOADV(V1, 9)
  PVM(6, V2)  LOADV(V2, 10)
  PVM(7, V3)  LOADV(V3, 11)
  PVM(8, V0)  LOADV(V0, 12)
  PVM(9, V1)  LOADV(V1, 13)
  PVM(10, V2) LOADV(V2, 14)
  PVM(11, V3) LOADV(V3, 15)
  PVM(12, V0) PVM(13, V1) PVM(14, V2) PVM(15, V3)
#undef LOADV
#undef PVM

#pragma unroll
  for (int n = 0; n < 4; ++n) {
    const int dcol = (ch * 4 + n) * 16;
#pragma unroll
    for (int i = 0; i < 4; ++i) {
      const int row = myrow + i;
      const float rs = reds[0][row] + reds[1][row];
      const float val = oacc[n][i] / rs;
      Og[((size_t)b * 512 + q0 + row) * 1024 + h * 128 + dcol + lr] = __float2bfloat16(val);
    }
  }
}

extern "C" void kernel_launch(void* const* d_in, const int* in_sizes, int n_in,
                              void* d_out, int out_size, void* d_ws, size_t ws_size,
                              hipStream_t stream) {
  (void)in_sizes; (void)n_in; (void)out_size; (void)ws_size;
  const float* x  = (const float*)d_in[0];
  const float* Wq = (const float*)d_in[1];
  const float* bq = (const float*)d_in[2];
  const float* Wk = (const float*)d_in[3];
  const float* bk = (const float*)d_in[4];
  const float* Wv = (const float*)d_in[5];
  const float* bv = (const float*)d_in[6];
  const float* W1 = (const float*)d_in[7];
  const float* b1 = (const float*)d_in[8];
  const float* W2 = (const float*)d_in[9];
  const float* b2 = (const float*)d_in[10];
  float* out = (float*)d_out;
  char* ws = (char*)d_ws;
  constexpr size_t MB = 1ull << 20;

  bf16* XB  = (bf16*)(ws + 0);
  bf16* WQT = (bf16*)(ws + 32 * MB);
  bf16* WKT = (bf16*)(ws + 34 * MB);
  bf16* WVT = (bf16*)(ws + 36 * MB);
  bf16* W1T = (bf16*)(ws + 38 * MB);
  bf16* W2T = (bf16*)(ws + 54 * MB);
  bf16* OB  = (bf16*)(ws + 70 * MB);
  bf16* QB  = (bf16*)(ws + 102 * MB);
  bf16* KB  = (bf16*)(ws + 134 * MB);
  bf16* VB  = (bf16*)(ws + 166 * MB);
  bf16* VT  = (bf16*)(ws + 0);        // overlays dead XB after QKV
  bf16* HC  = (bf16*)(ws + 102 * MB); // overlays dead QB/KB after attn

  k_cvt_bf16<<<2048, 256, 0, stream>>>(x, XB, (16384 * 1024) / 4);
  k_transpose_w<<<dim3(32, 32), 256, 0, stream>>>(Wq, WQT, 1024, 1024);
  k_transpose_w<<<dim3(32, 32), 256, 0, stream>>>(Wk, WKT, 1024, 1024);
  k_transpose_w<<<dim3(32, 32), 256, 0, stream>>>(Wv, WVT, 1024, 1024);
  k_transpose_w<<<dim3(256, 32), 256, 0, stream>>>(W1, W1T, 1024, 8192);
  k_transpose_w<<<dim3(32, 256), 256, 0, stream>>>(W2, W2T, 8192, 1024);

  // QKV projections (M=16384, N=1024, K=1024): grid (4, 64) = 256 wgs
  k_gemm256<0, false><<<dim3(4, 64), 512, 0, stream>>>(XB, WQT, bq, QB, 1024, 1024, 1024, 1024);
  k_gemm256<0, false><<<dim3(4, 64), 512, 0, stream>>>(XB, WKT, bk, KB, 1024, 1024, 1024, 1024);
  k_gemm256<0, false><<<dim3(4, 64), 512, 0, stream>>>(XB, WVT, bv, VB, 1024, 1024, 1024, 1024);

  k_transpose_v<<<dim3(16, 4, 256), 256, 0, stream>>>(VB, VT);
  k_attn<<<dim3(16, 256), 256, 0, stream>>>(QB, KB, VT, OB);

  // FFN chunked over F (4 x 2048)
  for (int chk = 0; chk < 4; ++chk) {
    k_gemm256<1, false><<<dim3(8, 64), 512, 0, stream>>>(
        OB, W1T + (size_t)chk * 2048 * 1024, b1 + chk * 2048, HC, 1024, 1024, 1024, 2048);
    if (chk == 0)
      k_gemm256<2, false><<<dim3(4, 64), 512, 0, stream>>>(
          HC, W2T + chk * 2048, b2, out, 2048, 2048, 8192, 1024);
    else
      k_gemm256<2, true><<<dim3(4, 64), 512, 0, stream>>>(
          HC, W2T + chk * 2048, nullptr, out, 2048, 2048, 8192, 1024);
  }
}

// Round 7
// 1104.081 us; speedup vs baseline: 1.0136x; 1.0136x over previous
//
#include <hip/hip_runtime.h>
#include <hip/hip_bf16.h>
#include <math.h>

typedef __attribute__((ext_vector_type(8))) short bf16x8;
typedef __attribute__((ext_vector_type(4))) float f32x4;
typedef __hip_bfloat16 bf16;

__device__ __forceinline__ void gload_lds16(const void* g, void* l) {
  __builtin_amdgcn_global_load_lds((const __attribute__((address_space(1))) void*)g,
                                   (__attribute__((address_space(3))) void*)l,
                                   16, 0, 0);
}

__device__ __forceinline__ float gelu_erf(float x) {
  return 0.5f * x * (1.0f + erff(x * 0.70710678118654752f));
}

// ---------------- convert f32 -> bf16 (vectorized) ----------------
__global__ __launch_bounds__(256) void k_cvt_bf16(const float* __restrict__ in,
                                                  bf16* __restrict__ out, int n4) {
  int i = blockIdx.x * 256 + threadIdx.x;
  const int stride = gridDim.x * 256;
  for (; i < n4; i += stride) {
    float4 v = reinterpret_cast<const float4*>(in)[i];
    bf16* o = out + (size_t)i * 4;
    o[0] = __float2bfloat16(v.x);
    o[1] = __float2bfloat16(v.y);
    o[2] = __float2bfloat16(v.z);
    o[3] = __float2bfloat16(v.w);
  }
}

// ---------------- transpose f32 [R][C] -> bf16 [C][R] ----------------
__global__ __launch_bounds__(256) void k_transpose_w(const float* __restrict__ in,
                                                     bf16* __restrict__ out,
                                                     int R, int C) {
  __shared__ float tile[32][33];
  const int c0 = blockIdx.x * 32, r0 = blockIdx.y * 32;
  const int tx = threadIdx.x & 31, ty = threadIdx.x >> 5;
  for (int i = 0; i < 32; i += 8)
    tile[ty + i][tx] = in[(size_t)(r0 + ty + i) * C + c0 + tx];
  __syncthreads();
  for (int i = 0; i < 32; i += 8)
    out[(size_t)(c0 + ty + i) * R + r0 + tx] = __float2bfloat16(tile[tx][ty + i]);
}

// ------------- per-head V transpose: [B*S][E] -> [(b*H+h)*128 + d][S] -------------
__global__ __launch_bounds__(256) void k_transpose_v(const bf16* __restrict__ Vb,
                                                     bf16* __restrict__ Vt) {
  __shared__ bf16 tile[32][34];
  const int bh = blockIdx.z;
  const int b = bh >> 3, h = bh & 7;
  const int s0 = blockIdx.x * 32, d0 = blockIdx.y * 32;
  const int tx = threadIdx.x & 31, ty = threadIdx.x >> 5;
  for (int i = 0; i < 32; i += 8)
    tile[ty + i][tx] = Vb[((size_t)b * 512 + s0 + ty + i) * 1024 + h * 128 + d0 + tx];
  __syncthreads();
  for (int i = 0; i < 32; i += 8)
    Vt[((size_t)bh * 128 + d0 + ty + i) * 512 + s0 + tx] = tile[tx][ty + i];
}

// ======== 256x256 tile, BK=64, 8-wave, 4-phase pipelined bf16 GEMM ========
// (reverted to round-4 version: best measured GEMM so far)
template <int EPI, bool ACC>
__global__ __launch_bounds__(512, 2) void k_gemm256(
    const bf16* __restrict__ A, const bf16* __restrict__ Bt,
    const float* __restrict__ bias, void* __restrict__ Cout,
    int K, int lda, int ldb, int ldc) {
  __shared__ __attribute__((aligned(16))) char lds[131072];
  const int t = threadIdx.x, w = t >> 6, l = t & 63;
  const int gx = gridDim.x, nwg = gx * gridDim.y;
  int bid = blockIdx.y * gx + blockIdx.x;
  bid = (bid & 7) * (nwg >> 3) + (bid >> 3);  // XCD swizzle (nwg % 8 == 0)
  const int bm = bid / gx, bn = bid % gx;
  const int wm = w >> 2, wn = w & 3;  // 2M x 4N waves, per-wave C = 128x64
  const int lq = l >> 4, lr = l & 15;

  const int srow = (w << 3) + (l >> 3);
  const int scol = ((l & 7) ^ ((l >> 3) & 7)) << 4;
  const size_t ldab = (size_t)lda * 2, ldbb = (size_t)ldb * 2;
  const size_t ldab64 = ldab * 64, ldbb64 = ldbb * 64;
  const char* pA = (const char*)(A + (size_t)(bm * 256) * lda) + (size_t)srow * ldab + scol;
  const char* pB = (const char*)(Bt + (size_t)(bn * 256) * ldb) + (size_t)srow * ldbb + scol;
  const int ldst = w * 1024;

  const int swz0 = (lq ^ (lr & 7)) << 4;
  const int arow = wm * 16384 + lr * 128;
  const int brow = 32768 + (wn >> 1) * 16384 + ((wn & 1) * 64 + lr) * 128;

  f32x4 acc[8][4];
#pragma unroll
  for (int m = 0; m < 8; ++m)
#pragma unroll
    for (int n = 0; n < 4; ++n) acc[m][n] = (f32x4){0.f, 0.f, 0.f, 0.f};

#define STAGE_A(j, slotbase)                                            \
  gload_lds16(pA + (size_t)(j)*ldab64, (slotbase) + (j)*8192 + ldst)
#define STAGE_B(j, slotbase)                                            \
  gload_lds16(pB + (size_t)(j)*ldbb64, (slotbase) + 32768 + (j)*8192 + ldst)

  {
    char* s0 = lds;
    STAGE_A(0, s0); STAGE_A(1, s0); STAGE_A(2, s0); STAGE_A(3, s0);
    STAGE_B(0, s0); STAGE_B(1, s0); STAGE_B(2, s0); STAGE_B(3, s0);
    pA += 128; pB += 128;
    asm volatile("s_waitcnt vmcnt(0)" ::: "memory");
    __builtin_amdgcn_s_barrier();
    asm volatile("" ::: "memory");
  }

  const int NT = K >> 6;
  bf16x8 aF[4][2], bF01[2][2], bF23[2][2];

  for (int kt = 0; kt < NT; ++kt) {
    char* cur = lds + (kt & 1) * 65536;
    char* nxt = lds + ((kt & 1) ^ 1) * 65536;
    const char* Ac = cur + arow;
    const char* Bc = cur + brow;
    const bool pre = (kt + 1 < NT);

#pragma unroll
    for (int fr = 0; fr < 4; ++fr)
#pragma unroll
      for (int kk = 0; kk < 2; ++kk)
        aF[fr][kk] = *(const bf16x8*)(Ac + fr * 2048 + (swz0 ^ (kk << 6)));
#pragma unroll
    for (int fc = 0; fc < 2; ++fc)
#pragma unroll
      for (int kk = 0; kk < 2; ++kk)
        bF01[fc][kk] = *(const bf16x8*)(Bc + fc * 2048 + (swz0 ^ (kk << 6)));
    if (pre) { STAGE_A(0, nxt); STAGE_A(1, nxt); STAGE_A(2, nxt); STAGE_A(3, nxt); }
    __builtin_amdgcn_s_barrier();
    __builtin_amdgcn_s_setprio(1);
#pragma unroll
    for (int fr = 0; fr < 4; ++fr)
#pragma unroll
      for (int fc = 0; fc < 2; ++fc)
#pragma unroll
        for (int kk = 0; kk < 2; ++kk)
          acc[fr][fc] = __builtin_amdgcn_mfma_f32_16x16x32_bf16(aF[fr][kk], bF01[fc][kk], acc[fr][fc], 0, 0, 0);
    __builtin_amdgcn_s_setprio(0);
    __builtin_amdgcn_s_barrier();

#pragma unroll
    for (int fc = 0; fc < 2; ++fc)
#pragma unroll
      for (int kk = 0; kk < 2; ++kk)
        bF23[fc][kk] = *(const bf16x8*)(Bc + (2 + fc) * 2048 + (swz0 ^ (kk << 6)));
    if (pre) { STAGE_B(0, nxt); STAGE_B(1, nxt); }
    __builtin_amdgcn_s_barrier();
    __builtin_amdgcn_s_setprio(1);
#pragma unroll
    for (int fr = 0; fr < 4; ++fr)
#pragma unroll
      for (int fc = 0; fc < 2; ++fc)
#pragma unroll
        for (int kk = 0; kk < 2; ++kk)
          acc[fr][2 + fc] = __builtin_amdgcn_mfma_f32_16x16x32_bf16(aF[fr][kk], bF23[fc][kk], acc[fr][2 + fc], 0, 0, 0);
    __builtin_amdgcn_s_setprio(0);
    __builtin_amdgcn_s_barrier();

#pragma unroll
    for (int fr = 0; fr < 4; ++fr)
#pragma unroll
      for (int kk = 0; kk < 2; ++kk)
        aF[fr][kk] = *(const bf16x8*)(Ac + (4 + fr) * 2048 + (swz0 ^ (kk << 6)));
    if (pre) { STAGE_B(2, nxt); STAGE_B(3, nxt); }
    __builtin_amdgcn_s_barrier();
    __builtin_amdgcn_s_setprio(1);
#pragma unroll
    for (int fr = 0; fr < 4; ++fr)
#pragma unroll
      for (int fc = 0; fc < 2; ++fc)
#pragma unroll
        for (int kk = 0; kk < 2; ++kk)
          acc[4 + fr][fc] = __builtin_amdgcn_mfma_f32_16x16x32_bf16(aF[fr][kk], bF01[fc][kk], acc[4 + fr][fc], 0, 0, 0);
    __builtin_amdgcn_s_setprio(0);
    __builtin_amdgcn_s_barrier();

    __builtin_amdgcn_s_setprio(1);
#pragma unroll
    for (int fr = 0; fr < 4; ++fr)
#pragma unroll
      for (int fc = 0; fc < 2; ++fc)
#pragma unroll
        for (int kk = 0; kk < 2; ++kk)
          acc[4 + fr][2 + fc] = __builtin_amdgcn_mfma_f32_16x16x32_bf16(aF[fr][kk], bF23[fc][kk], acc[4 + fr][2 + fc], 0, 0, 0);
    __builtin_amdgcn_s_setprio(0);
    asm volatile("s_waitcnt vmcnt(0)" ::: "memory");
    __builtin_amdgcn_s_barrier();
    asm volatile("" ::: "memory");

    if (pre) { pA += 128; pB += 128; }
  }
#undef STAGE_A
#undef STAGE_B

  const int rowb = bm * 256 + wm * 128;
  const int colb = bn * 256 + wn * 64;
#pragma unroll
  for (int fr = 0; fr < 8; ++fr) {
#pragma unroll
    for (int fc = 0; fc < 4; ++fc) {
      const int col = colb + fc * 16 + lr;
      const float bv = bias ? bias[col] : 0.0f;
#pragma unroll
      for (int i = 0; i < 4; ++i) {
        const int row = rowb + fr * 16 + lq * 4 + i;
        float v = acc[fr][fc][i] + bv;
        if (EPI == 1) v = gelu_erf(v);
        if (EPI <= 1) {
          ((bf16*)Cout)[(size_t)row * ldc + col] = __float2bfloat16(v);
        } else {
          float* Cf = (float*)Cout;
          const size_t idx = (size_t)row * ldc + col;
          if (ACC) v += Cf[idx];
          Cf[idx] = v;
        }
      }
    }
  }
}

// ---------------- attention v4: half-size P buffer -> 2x occupancy ----------------
// Same math as v2/v3 (register softmax, Pl bounce). Pl shrunk to [32][264] (16.5KB):
// P's two column-halves are written/consumed in two PV passes, so total LDS ~17.5KB
// (was 33.8KB) -> LDS limit 9 blocks/CU; VGPR becomes binding (~5-6 blocks/CU).
__global__ __launch_bounds__(256) void k_attn(const bf16* __restrict__ Qg,
                                              const bf16* __restrict__ Kg,
                                              const bf16* __restrict__ Vt,
                                              bf16* __restrict__ Og) {
  __shared__ unsigned short Pl[32][264];
  __shared__ float redm[2][32];
  __shared__ float reds[2][32];
  int bid = blockIdx.y * 16 + blockIdx.x;
  bid = (bid & 7) * (4096 >> 3) + (bid >> 3);
  const int bh = bid / 16, q0 = (bid % 16) * 32;
  const int b = bh >> 3, h = bh & 7;
  const int t = threadIdx.x, w = t >> 6, l = t & 63;
  const int lq = l >> 4, lr = l & 15;
  const int rt = w & 1, ch = w >> 1;
  const int myrow = rt * 16 + lq * 4;

  // Q fragments (rows rt*16+lr, k = d0*32 + lq*8)
  const bf16* qbase = Qg + ((size_t)b * 512 + q0 + rt * 16 + lr) * 1024 + h * 128;
  bf16x8 afr[4];
#pragma unroll
  for (int d0 = 0; d0 < 4; ++d0)
    afr[d0] = *(const bf16x8*)(qbase + d0 * 32 + lq * 8);

  // ---- QK^T (4-buffer rotation; wave covers rows rt*16..+16, cols ch*256..+256) ----
  const bf16* kb2 = Kg + (size_t)b * 512 * 1024 + h * 128 +
                    (size_t)(ch * 256 + lr) * 1024 + lq * 8;
  f32x4 sc[16];
  bf16x8 K0[4], K1[4], K2[4], K3[4];

#define LOADK(BUF, CT)                                                   \
  {                                                                      \
    _Pragma("unroll") for (int d0 = 0; d0 < 4; ++d0)                     \
        BUF[d0] = *(const bf16x8*)(kb2 + (CT)*16384 + d0 * 32);          \
  }
#define QKT(CT, BUF)                                                     \
  {                                                                      \
    f32x4 a = (f32x4){0.f, 0.f, 0.f, 0.f};                               \
    _Pragma("unroll") for (int d0 = 0; d0 < 4; ++d0)                     \
        a = __builtin_amdgcn_mfma_f32_16x16x32_bf16(afr[d0], BUF[d0], a, 0, 0, 0); \
    sc[CT] = a;                                                          \
  }

  LOADK(K0, 0) LOADK(K1, 1) LOADK(K2, 2) LOADK(K3, 3)
  QKT(0, K0)  LOADK(K0, 4)
  QKT(1, K1)  LOADK(K1, 5)
  QKT(2, K2)  LOADK(K2, 6)
  QKT(3, K3)  LOADK(K3, 7)
  QKT(4, K0)  LOADK(K0, 8)
  QKT(5, K1)  LOADK(K1, 9)
  QKT(6, K2)  LOADK(K2, 10)
  QKT(7, K3)  LOADK(K3, 11)
  QKT(8, K0)  LOADK(K0, 12)
  QKT(9, K1)  LOADK(K1, 13)
  QKT(10, K2) LOADK(K2, 14)
  QKT(11, K3) LOADK(K3, 15)
  QKT(12, K0) QKT(13, K1) QKT(14, K2) QKT(15, K3)
#undef LOADK
#undef QKT

  // ---- row max: per-lane partial, lr-group reduce, cross-wave via redm ----
  float m4[4];
#pragma unroll
  for (int i = 0; i < 4; ++i) {
    float m = sc[0][i];
#pragma unroll
    for (int ct = 1; ct < 16; ++ct) m = fmaxf(m, sc[ct][i]);
    m4[i] = m;
  }
#pragma unroll
  for (int i = 0; i < 4; ++i) {
    m4[i] = fmaxf(m4[i], __shfl_xor(m4[i], 1));
    m4[i] = fmaxf(m4[i], __shfl_xor(m4[i], 2));
    m4[i] = fmaxf(m4[i], __shfl_xor(m4[i], 4));
    m4[i] = fmaxf(m4[i], __shfl_xor(m4[i], 8));
  }
  if (lr == 0) {
#pragma unroll
    for (int i = 0; i < 4; ++i) redm[ch][myrow + i] = m4[i];
  }
  __syncthreads();  // (1) redm visible
  float fm[4];
#pragma unroll
  for (int i = 0; i < 4; ++i)
    fm[i] = fmaxf(redm[0][myrow + i], redm[1][myrow + i]);

  // ---- exp: pack P as bf16 pairs into regs (sc dies), partial row-sum ----
  float s4[4] = {0.f, 0.f, 0.f, 0.f};
  unsigned int pk[32];
#pragma unroll
  for (int ct = 0; ct < 16; ++ct) {
    float e0 = __expf(sc[ct][0] - fm[0]);
    float e1 = __expf(sc[ct][1] - fm[1]);
    float e2 = __expf(sc[ct][2] - fm[2]);
    float e3 = __expf(sc[ct][3] - fm[3]);
    s4[0] += e0; s4[1] += e1; s4[2] += e2; s4[3] += e3;
    unsigned short u0 = __bfloat16_as_ushort(__float2bfloat16(e0));
    unsigned short u1 = __bfloat16_as_ushort(__float2bfloat16(e1));
    unsigned short u2 = __bfloat16_as_ushort(__float2bfloat16(e2));
    unsigned short u3 = __bfloat16_as_ushort(__float2bfloat16(e3));
    pk[ct * 2 + 0] = (unsigned)u0 | ((unsigned)u1 << 16);
    pk[ct * 2 + 1] = (unsigned)u2 | ((unsigned)u3 << 16);
  }
#pragma unroll
  for (int i = 0; i < 4; ++i) {
    s4[i] += __shfl_xor(s4[i], 1);
    s4[i] += __shfl_xor(s4[i], 2);
    s4[i] += __shfl_xor(s4[i], 4);
    s4[i] += __shfl_xor(s4[i], 8);
  }
  if (lr == 0) {
#pragma unroll
    for (int i = 0; i < 4; ++i) reds[ch][myrow + i] = s4[i];
  }

  // ---- P half 0 (cols 0-255, written by ch==0 waves) ----
  if (ch == 0) {
#pragma unroll
    for (int ct = 0; ct < 16; ++ct)
#pragma unroll
      for (int j = 0; j < 2; ++j) {
        const unsigned v = pk[ct * 2 + j];
        Pl[myrow + 2 * j + 0][ct * 16 + lr] = (unsigned short)(v & 0xffffu);
        Pl[myrow + 2 * j + 1][ct * 16 + lr] = (unsigned short)(v >> 16);
      }
  }
  __syncthreads();  // (2) P half 0 + reds visible

  // ---- PV pass 0: kv 0..255 ----
  const bf16* vbase = Vt + (size_t)bh * 128 * 512;
  f32x4 oacc[4];
#pragma unroll
  for (int n = 0; n < 4; ++n) oacc[n] = (f32x4){0.f, 0.f, 0.f, 0.f};
  for (int s0 = 0; s0 < 256; s0 += 32) {
    bf16x8 pa = *(const bf16x8*)&Pl[rt * 16 + lr][s0 + lq * 8];
#pragma unroll
    for (int n = 0; n < 4; ++n) {
      const int dcol = (ch * 4 + n) * 16;
      bf16x8 vb = *(const bf16x8*)(vbase + (size_t)(dcol + lr) * 512 + s0 + lq * 8);
      oacc[n] = __builtin_amdgcn_mfma_f32_16x16x32_bf16(pa, vb, oacc[n], 0, 0, 0);
    }
  }
  __syncthreads();  // (3) PV pass 0 done reading Pl

  // ---- P half 1 (cols 256-511, written by ch==1 waves) ----
  if (ch == 1) {
#pragma unroll
    for (int ct = 0; ct < 16; ++ct)
#pragma unroll
      for (int j = 0; j < 2; ++j) {
        const unsigned v = pk[ct * 2 + j];
        Pl[myrow + 2 * j + 0][ct * 16 + lr] = (unsigned short)(v & 0xffffu);
        Pl[myrow + 2 * j + 1][ct * 16 + lr] = (unsigned short)(v >> 16);
      }
  }
  __syncthreads();  // (4) P half 1 visible

  // ---- PV pass 1: kv 256..511 ----
  for (int s0 = 0; s0 < 256; s0 += 32) {
    bf16x8 pa = *(const bf16x8*)&Pl[rt * 16 + lr][s0 + lq * 8];
#pragma unroll
    for (int n = 0; n < 4; ++n) {
      const int dcol = (ch * 4 + n) * 16;
      bf16x8 vb = *(const bf16x8*)(vbase + (size_t)(dcol + lr) * 512 + 256 + s0 + lq * 8);
      oacc[n] = __builtin_amdgcn_mfma_f32_16x16x32_bf16(pa, vb, oacc[n], 0, 0, 0);
    }
  }

#pragma unroll
  for (int n = 0; n < 4; ++n) {
    const int dcol = (ch * 4 + n) * 16;
#pragma unroll
    for (int i = 0; i < 4; ++i) {
      const int row = myrow + i;
      const float rs = reds[0][row] + reds[1][row];
      const float val = oacc[n][i] / rs;
      Og[((size_t)b * 512 + q0 + row) * 1024 + h * 128 + dcol + lr] = __float2bfloat16(val);
    }
  }
}

extern "C" void kernel_launch(void* const* d_in, const int* in_sizes, int n_in,
                              void* d_out, int out_size, void* d_ws, size_t ws_size,
                              hipStream_t stream) {
  (void)in_sizes; (void)n_in; (void)out_size; (void)ws_size;
  const float* x  = (const float*)d_in[0];
  const float* Wq = (const float*)d_in[1];
  const float* bq = (const float*)d_in[2];
  const float* Wk = (const float*)d_in[3];
  const float* bk = (const float*)d_in[4];
  const float* Wv = (const float*)d_in[5];
  const float* bv = (const float*)d_in[6];
  const float* W1 = (const float*)d_in[7];
  const float* b1 = (const float*)d_in[8];
  const float* W2 = (const float*)d_in[9];
  const float* b2 = (const float*)d_in[10];
  float* out = (float*)d_out;
  char* ws = (char*)d_ws;
  constexpr size_t MB = 1ull << 20;

  bf16* XB  = (bf16*)(ws + 0);
  bf16* WQT = (bf16*)(ws + 32 * MB);
  bf16* WKT = (bf16*)(ws + 34 * MB);
  bf16* WVT = (bf16*)(ws + 36 * MB);
  bf16* W1T = (bf16*)(ws + 38 * MB);
  bf16* W2T = (bf16*)(ws + 54 * MB);
  bf16* OB  = (bf16*)(ws + 70 * MB);
  bf16* QB  = (bf16*)(ws + 102 * MB);
  bf16* KB  = (bf16*)(ws + 134 * MB);
  bf16* VB  = (bf16*)(ws + 166 * MB);
  bf16* VT  = (bf16*)(ws + 0);        // overlays dead XB after QKV
  bf16* HC  = (bf16*)(ws + 102 * MB); // overlays dead QB/KB after attn

  k_cvt_bf16<<<2048, 256, 0, stream>>>(x, XB, (16384 * 1024) / 4);
  k_transpose_w<<<dim3(32, 32), 256, 0, stream>>>(Wq, WQT, 1024, 1024);
  k_transpose_w<<<dim3(32, 32), 256, 0, stream>>>(Wk, WKT, 1024, 1024);
  k_transpose_w<<<dim3(32, 32), 256, 0, stream>>>(Wv, WVT, 1024, 1024);
  k_transpose_w<<<dim3(256, 32), 256, 0, stream>>>(W1, W1T, 1024, 8192);
  k_transpose_w<<<dim3(32, 256), 256, 0, stream>>>(W2, W2T, 8192, 1024);

  // QKV projections (M=16384, N=1024, K=1024): grid (4, 64) = 256 wgs
  k_gemm256<0, false><<<dim3(4, 64), 512, 0, stream>>>(XB, WQT, bq, QB, 1024, 1024, 1024, 1024);
  k_gemm256<0, false><<<dim3(4, 64), 512, 0, stream>>>(XB, WKT, bk, KB, 1024, 1024, 1024, 1024);
  k_gemm256<0, false><<<dim3(4, 64), 512, 0, stream>>>(XB, WVT, bv, VB, 1024, 1024, 1024, 1024);

  k_transpose_v<<<dim3(16, 4, 256), 256, 0, stream>>>(VB, VT);
  k_attn<<<dim3(16, 256), 256, 0, stream>>>(QB, KB, VT, OB);

  // FFN chunked over F (4 x 2048)
  for (int chk = 0; chk < 4; ++chk) {
    k_gemm256<1, false><<<dim3(8, 64), 512, 0, stream>>>(
        OB, W1T + (size_t)chk * 2048 * 1024, b1 + chk * 2048, HC, 1024, 1024, 1024, 2048);
    if (chk == 0)
      k_gemm256<2, false><<<dim3(4, 64), 512, 0, stream>>>(
          HC, W2T + chk * 2048, b2, out, 2048, 2048, 8192, 1024);
    else
      k_gemm256<2, true><<<dim3(4, 64), 512, 0, stream>>>(
          HC, W2T + chk * 2048, nullptr, out, 2048, 2048, 8192, 1024);
  }
}

// Round 8
// 987.009 us; speedup vs baseline: 1.1338x; 1.1186x over previous
//
#include <hip/hip_runtime.h>
#include <hip/hip_bf16.h>
#include <math.h>

typedef __attribute__((ext_vector_type(8))) short bf16x8;
typedef __attribute__((ext_vector_type(4))) float f32x4;
typedef __hip_bfloat16 bf16;

__device__ __forceinline__ void gload_lds16(const void* g, void* l) {
  __builtin_amdgcn_global_load_lds((const __attribute__((address_space(1))) void*)g,
                                   (__attribute__((address_space(3))) void*)l,
                                   16, 0, 0);
}

__device__ __forceinline__ float gelu_erf(float x) {
  return 0.5f * x * (1.0f + erff(x * 0.70710678118654752f));
}

// ---------------- convert f32 -> bf16 (vectorized) ----------------
__global__ __launch_bounds__(256) void k_cvt_bf16(const float* __restrict__ in,
                                                  bf16* __restrict__ out, int n4) {
  int i = blockIdx.x * 256 + threadIdx.x;
  const int stride = gridDim.x * 256;
  for (; i < n4; i += stride) {
    float4 v = reinterpret_cast<const float4*>(in)[i];
    bf16* o = out + (size_t)i * 4;
    o[0] = __float2bfloat16(v.x);
    o[1] = __float2bfloat16(v.y);
    o[2] = __float2bfloat16(v.z);
    o[3] = __float2bfloat16(v.w);
  }
}

// ---------------- transpose f32 [R][C] -> bf16 [C][R] ----------------
__global__ __launch_bounds__(256) void k_transpose_w(const float* __restrict__ in,
                                                     bf16* __restrict__ out,
                                                     int R, int C) {
  __shared__ float tile[32][33];
  const int c0 = blockIdx.x * 32, r0 = blockIdx.y * 32;
  const int tx = threadIdx.x & 31, ty = threadIdx.x >> 5;
  for (int i = 0; i < 32; i += 8)
    tile[ty + i][tx] = in[(size_t)(r0 + ty + i) * C + c0 + tx];
  __syncthreads();
  for (int i = 0; i < 32; i += 8)
    out[(size_t)(c0 + ty + i) * R + r0 + tx] = __float2bfloat16(tile[tx][ty + i]);
}

// ------------- per-head V transpose: [B*S][E] -> [(b*H+h)*128 + d][S] -------------
__global__ __launch_bounds__(256) void k_transpose_v(const bf16* __restrict__ Vb,
                                                     bf16* __restrict__ Vt) {
  __shared__ bf16 tile[32][34];
  const int bh = blockIdx.z;
  const int b = bh >> 3, h = bh & 7;
  const int s0 = blockIdx.x * 32, d0 = blockIdx.y * 32;
  const int tx = threadIdx.x & 31, ty = threadIdx.x >> 5;
  for (int i = 0; i < 32; i += 8)
    tile[ty + i][tx] = Vb[((size_t)b * 512 + s0 + ty + i) * 1024 + h * 128 + d0 + tx];
  __syncthreads();
  for (int i = 0; i < 32; i += 8)
    Vt[((size_t)bh * 128 + d0 + ty + i) * 512 + s0 + tx] = tile[tx][ty + i];
}

// ======== 256x256 tile, BK=64, 8-wave, 4-phase pipelined bf16 GEMM (R4, best) ========
template <int EPI, bool ACC>
__global__ __launch_bounds__(512, 2) void k_gemm256(
    const bf16* __restrict__ A, const bf16* __restrict__ Bt,
    const float* __restrict__ bias, void* __restrict__ Cout,
    int K, int lda, int ldb, int ldc) {
  __shared__ __attribute__((aligned(16))) char lds[131072];
  const int t = threadIdx.x, w = t >> 6, l = t & 63;
  const int gx = gridDim.x, nwg = gx * gridDim.y;
  int bid = blockIdx.y * gx + blockIdx.x;
  bid = (bid & 7) * (nwg >> 3) + (bid >> 3);  // XCD swizzle (nwg % 8 == 0)
  const int bm = bid / gx, bn = bid % gx;
  const int wm = w >> 2, wn = w & 3;
  const int lq = l >> 4, lr = l & 15;

  const int srow = (w << 3) + (l >> 3);
  const int scol = ((l & 7) ^ ((l >> 3) & 7)) << 4;
  const size_t ldab = (size_t)lda * 2, ldbb = (size_t)ldb * 2;
  const size_t ldab64 = ldab * 64, ldbb64 = ldbb * 64;
  const char* pA = (const char*)(A + (size_t)(bm * 256) * lda) + (size_t)srow * ldab + scol;
  const char* pB = (const char*)(Bt + (size_t)(bn * 256) * ldb) + (size_t)srow * ldbb + scol;
  const int ldst = w * 1024;

  const int swz0 = (lq ^ (lr & 7)) << 4;
  const int arow = wm * 16384 + lr * 128;
  const int brow = 32768 + (wn >> 1) * 16384 + ((wn & 1) * 64 + lr) * 128;

  f32x4 acc[8][4];
#pragma unroll
  for (int m = 0; m < 8; ++m)
#pragma unroll
    for (int n = 0; n < 4; ++n) acc[m][n] = (f32x4){0.f, 0.f, 0.f, 0.f};

#define STAGE_A(j, slotbase)                                            \
  gload_lds16(pA + (size_t)(j)*ldab64, (slotbase) + (j)*8192 + ldst)
#define STAGE_B(j, slotbase)                                            \
  gload_lds16(pB + (size_t)(j)*ldbb64, (slotbase) + 32768 + (j)*8192 + ldst)

  {
    char* s0 = lds;
    STAGE_A(0, s0); STAGE_A(1, s0); STAGE_A(2, s0); STAGE_A(3, s0);
    STAGE_B(0, s0); STAGE_B(1, s0); STAGE_B(2, s0); STAGE_B(3, s0);
    pA += 128; pB += 128;
    asm volatile("s_waitcnt vmcnt(0)" ::: "memory");
    __builtin_amdgcn_s_barrier();
    asm volatile("" ::: "memory");
  }

  const int NT = K >> 6;
  bf16x8 aF[4][2], bF01[2][2], bF23[2][2];

  for (int kt = 0; kt < NT; ++kt) {
    char* cur = lds + (kt & 1) * 65536;
    char* nxt = lds + ((kt & 1) ^ 1) * 65536;
    const char* Ac = cur + arow;
    const char* Bc = cur + brow;
    const bool pre = (kt + 1 < NT);

#pragma unroll
    for (int fr = 0; fr < 4; ++fr)
#pragma unroll
      for (int kk = 0; kk < 2; ++kk)
        aF[fr][kk] = *(const bf16x8*)(Ac + fr * 2048 + (swz0 ^ (kk << 6)));
#pragma unroll
    for (int fc = 0; fc < 2; ++fc)
#pragma unroll
      for (int kk = 0; kk < 2; ++kk)
        bF01[fc][kk] = *(const bf16x8*)(Bc + fc * 2048 + (swz0 ^ (kk << 6)));
    if (pre) { STAGE_A(0, nxt); STAGE_A(1, nxt); STAGE_A(2, nxt); STAGE_A(3, nxt); }
    __builtin_amdgcn_s_barrier();
    __builtin_amdgcn_s_setprio(1);
#pragma unroll
    for (int fr = 0; fr < 4; ++fr)
#pragma unroll
      for (int fc = 0; fc < 2; ++fc)
#pragma unroll
        for (int kk = 0; kk < 2; ++kk)
          acc[fr][fc] = __builtin_amdgcn_mfma_f32_16x16x32_bf16(aF[fr][kk], bF01[fc][kk], acc[fr][fc], 0, 0, 0);
    __builtin_amdgcn_s_setprio(0);
    __builtin_amdgcn_s_barrier();

#pragma unroll
    for (int fc = 0; fc < 2; ++fc)
#pragma unroll
      for (int kk = 0; kk < 2; ++kk)
        bF23[fc][kk] = *(const bf16x8*)(Bc + (2 + fc) * 2048 + (swz0 ^ (kk << 6)));
    if (pre) { STAGE_B(0, nxt); STAGE_B(1, nxt); }
    __builtin_amdgcn_s_barrier();
    __builtin_amdgcn_s_setprio(1);
#pragma unroll
    for (int fr = 0; fr < 4; ++fr)
#pragma unroll
      for (int fc = 0; fc < 2; ++fc)
#pragma unroll
        for (int kk = 0; kk < 2; ++kk)
          acc[fr][2 + fc] = __builtin_amdgcn_mfma_f32_16x16x32_bf16(aF[fr][kk], bF23[fc][kk], acc[fr][2 + fc], 0, 0, 0);
    __builtin_amdgcn_s_setprio(0);
    __builtin_amdgcn_s_barrier();

#pragma unroll
    for (int fr = 0; fr < 4; ++fr)
#pragma unroll
      for (int kk = 0; kk < 2; ++kk)
        aF[fr][kk] = *(const bf16x8*)(Ac + (4 + fr) * 2048 + (swz0 ^ (kk << 6)));
    if (pre) { STAGE_B(2, nxt); STAGE_B(3, nxt); }
    __builtin_amdgcn_s_barrier();
    __builtin_amdgcn_s_setprio(1);
#pragma unroll
    for (int fr = 0; fr < 4; ++fr)
#pragma unroll
      for (int fc = 0; fc < 2; ++fc)
#pragma unroll
        for (int kk = 0; kk < 2; ++kk)
          acc[4 + fr][fc] = __builtin_amdgcn_mfma_f32_16x16x32_bf16(aF[fr][kk], bF01[fc][kk], acc[4 + fr][fc], 0, 0, 0);
    __builtin_amdgcn_s_setprio(0);
    __builtin_amdgcn_s_barrier();

    __builtin_amdgcn_s_setprio(1);
#pragma unroll
    for (int fr = 0; fr < 4; ++fr)
#pragma unroll
      for (int fc = 0; fc < 2; ++fc)
#pragma unroll
        for (int kk = 0; kk < 2; ++kk)
          acc[4 + fr][2 + fc] = __builtin_amdgcn_mfma_f32_16x16x32_bf16(aF[fr][kk], bF23[fc][kk], acc[4 + fr][2 + fc], 0, 0, 0);
    __builtin_amdgcn_s_setprio(0);
    asm volatile("s_waitcnt vmcnt(0)" ::: "memory");
    __builtin_amdgcn_s_barrier();
    asm volatile("" ::: "memory");

    if (pre) { pA += 128; pB += 128; }
  }
#undef STAGE_A
#undef STAGE_B

  const int rowb = bm * 256 + wm * 128;
  const int colb = bn * 256 + wn * 64;
#pragma unroll
  for (int fr = 0; fr < 8; ++fr) {
#pragma unroll
    for (int fc = 0; fc < 4; ++fc) {
      const int col = colb + fc * 16 + lr;
      const float bv = bias ? bias[col] : 0.0f;
#pragma unroll
      for (int i = 0; i < 4; ++i) {
        const int row = rowb + fr * 16 + lq * 4 + i;
        float v = acc[fr][fc][i] + bv;
        if (EPI == 1) v = gelu_erf(v);
        if (EPI <= 1) {
          ((bf16*)Cout)[(size_t)row * ldc + col] = __float2bfloat16(v);
        } else {
          float* Cf = (float*)Cout;
          const size_t idx = (size_t)row * ldc + col;
          if (ACC) v += Cf[idx];
          Cf[idx] = v;
        }
      }
    }
  }
}

// ======== attention v5: GEMM-style, K fully LDS-resident, counted-vmcnt V pipeline ========
// Block = 512 threads (8 waves: wm=w>>2 rows, wn=w&3 cols), one (b,h,128-q-tile).
// LDS 128KB: QK phase = all K [512 rows][256B, 16-slot XOR swizzle]. PV phase (K dead):
// V dbuf 2x32KB @0, P chunk 32KB @64KB, red 4KB @96KB. Raw s_barrier + manual
// lgkmcnt/vmcnt (counted, never 0 mid-pipeline). Swizzle: LDS[r][s^(r&15)] = G[r][s].
__global__ __launch_bounds__(512, 1) void k_attn(const bf16* __restrict__ Qg,
                                                 const bf16* __restrict__ Kg,
                                                 const bf16* __restrict__ Vt,
                                                 bf16* __restrict__ Og) {
  __shared__ __attribute__((aligned(16))) char lds[131072];
  int bid = blockIdx.x;
  bid = (bid & 7) * 128 + (bid >> 3);  // XCD swizzle, 1024 = 8*128
  const int bh = bid >> 2, q0 = (bid & 3) * 128;
  const int b = bh >> 3, h = bh & 7;
  const int t = threadIdx.x, w = t >> 6, l = t & 63;
  const int lq = l >> 4, lr = l & 15;
  const int wm = w >> 2, wn = w & 3;

  // ---- stage ALL K (512x128 bf16 = 128KB), source pre-swizzled ----
  const int sr = t >> 4;                // base row 0..31 (per round +32)
  const int ss = (t & 15) ^ (sr & 15);  // inverse-swizzled source 16B slot
  {
    const bf16* ks = Kg + ((size_t)b * 512 + sr) * 1024 + h * 128 + ss * 8;
#pragma unroll
    for (int j = 0; j < 16; ++j)
      gload_lds16(ks + (size_t)j * 32 * 1024, lds + j * 8192 + w * 1024);
  }

  // ---- Q fragments to registers (rows q0+wm*64+fr*16+lr, k=d0*32+lq*8) ----
  bf16x8 qf[4][4];
  {
    const bf16* qb = Qg + ((size_t)b * 512 + q0 + wm * 64 + lr) * 1024 + h * 128 + lq * 8;
#pragma unroll
    for (int fr = 0; fr < 4; ++fr)
#pragma unroll
      for (int d0 = 0; d0 < 4; ++d0)
        qf[fr][d0] = *(const bf16x8*)(qb + (size_t)(fr * 16) * 1024 + d0 * 32);
  }

  asm volatile("s_waitcnt vmcnt(0)" ::: "memory");
  __builtin_amdgcn_s_barrier();
  asm volatile("" ::: "memory");

  // ---- QK^T: wave computes S rows wm*64..+64, cols wn*128..+128 ----
  f32x4 accS[4][8];
#pragma unroll
  for (int fr = 0; fr < 4; ++fr)
#pragma unroll
    for (int fc = 0; fc < 8; ++fc) accS[fr][fc] = (f32x4){0.f, 0.f, 0.f, 0.f};

  __builtin_amdgcn_s_setprio(1);
#pragma unroll
  for (int fc = 0; fc < 8; ++fc) {
    bf16x8 kf[4];
#pragma unroll
    for (int d0 = 0; d0 < 4; ++d0)
      kf[d0] = *(const bf16x8*)(lds + (wn * 128 + fc * 16 + lr) * 256 +
                                (((d0 * 4 + lq) ^ lr) << 4));
#pragma unroll
    for (int d0 = 0; d0 < 4; ++d0)
#pragma unroll
      for (int fr = 0; fr < 4; ++fr)
        accS[fr][fc] = __builtin_amdgcn_mfma_f32_16x16x32_bf16(qf[fr][d0], kf[d0], accS[fr][fc], 0, 0, 0);
  }
  __builtin_amdgcn_s_setprio(0);

  __builtin_amdgcn_s_barrier();  // all K reads done -> K region reusable
  asm volatile("" ::: "memory");

  // ---- issue V chunks 0,1 (V^T rows d=0..127, chunk = 128 kv cols = 256B/row) ----
  const bf16* vs = Vt + ((size_t)bh * 128 + sr) * 512 + ss * 8;
#define IVC(kc, slot)                                                         \
  {                                                                           \
    _Pragma("unroll") for (int j = 0; j < 4; ++j)                             \
        gload_lds16(vs + (size_t)j * 32 * 512 + (kc) * 128,                   \
                    lds + (slot) * 32768 + j * 8192 + w * 1024);              \
  }
  IVC(0, 0)
  IVC(1, 1)

  // ---- softmax: row max (local -> shfl over lr -> cross-wave via redm) ----
  float* redm = (float*)(lds + 98304);   // [4 wn][128 rows]
  float* reds = (float*)(lds + 100352);  // [4 wn][128 rows]
  float fm[4][4];
#pragma unroll
  for (int fr = 0; fr < 4; ++fr)
#pragma unroll
    for (int i = 0; i < 4; ++i) {
      float m = accS[fr][0][i];
#pragma unroll
      for (int fc = 1; fc < 8; ++fc) m = fmaxf(m, accS[fr][fc][i]);
      m = fmaxf(m, __shfl_xor(m, 1));
      m = fmaxf(m, __shfl_xor(m, 2));
      m = fmaxf(m, __shfl_xor(m, 4));
      m = fmaxf(m, __shfl_xor(m, 8));
      if (lr == 0) redm[wn * 128 + wm * 64 + fr * 16 + lq * 4 + i] = m;
    }
  asm volatile("s_waitcnt lgkmcnt(0)" ::: "memory");
  __builtin_amdgcn_s_barrier();
  asm volatile("" ::: "memory");
#pragma unroll
  for (int fr = 0; fr < 4; ++fr)
#pragma unroll
    for (int i = 0; i < 4; ++i) {
      const int row = wm * 64 + fr * 16 + lq * 4 + i;
      fm[fr][i] = fmaxf(fmaxf(redm[row], redm[128 + row]),
                        fmaxf(redm[256 + row], redm[384 + row]));
    }

  // ---- PV: 4 chunks; P chunk written by waves wn==kc, consumed by all ----
  f32x4 oacc[4][2];
#pragma unroll
  for (int fr = 0; fr < 4; ++fr)
#pragma unroll
    for (int fc = 0; fc < 2; ++fc) oacc[fr][fc] = (f32x4){0.f, 0.f, 0.f, 0.f};
  float s4[4][4];
#pragma unroll
  for (int fr = 0; fr < 4; ++fr)
#pragma unroll
    for (int i = 0; i < 4; ++i) s4[fr][i] = 0.f;

#define EXPWRITE(kc)                                                           \
  if (wn == (kc)) {                                                            \
    _Pragma("unroll") for (int fr = 0; fr < 4; ++fr)                           \
      _Pragma("unroll") for (int i = 0; i < 4; ++i) {                          \
        const int row = wm * 64 + fr * 16 + lq * 4 + i;                        \
        const int rx = lq * 4 + i;                                             \
        _Pragma("unroll") for (int fc = 0; fc < 8; ++fc) {                     \
          const float e = __expf(accS[fr][fc][i] - fm[fr][i]);                 \
          s4[fr][i] += e;                                                      \
          *(unsigned short*)(lds + 65536 + row * 256 +                         \
                             (((fc * 2 + (lr >> 3)) ^ rx) << 4) + (lr & 7) * 2) = \
              __bfloat16_as_ushort(__float2bfloat16(e));                       \
        }                                                                      \
      }                                                                        \
  }

#define PVMFMA(kc)                                                             \
  {                                                                            \
    const char* Vb = lds + ((kc) & 1) * 32768;                                 \
    __builtin_amdgcn_s_setprio(1);                                             \
    _Pragma("unroll") for (int kk = 0; kk < 4; ++kk) {                         \
      bf16x8 pa[4], vb[2];                                                     \
      _Pragma("unroll") for (int fr = 0; fr < 4; ++fr)                         \
          pa[fr] = *(const bf16x8*)(lds + 65536 + (wm * 64 + fr * 16 + lr) * 256 + \
                                    (((kk * 4 + lq) ^ lr) << 4));              \
      _Pragma("unroll") for (int fc = 0; fc < 2; ++fc)                         \
          vb[fc] = *(const bf16x8*)(Vb + (wn * 32 + fc * 16 + lr) * 256 +      \
                                    (((kk * 4 + lq) ^ lr) << 4));              \
      _Pragma("unroll") for (int fr = 0; fr < 4; ++fr)                         \
        _Pragma("unroll") for (int fc = 0; fc < 2; ++fc)                       \
          oacc[fr][fc] = __builtin_amdgcn_mfma_f32_16x16x32_bf16(pa[fr], vb[fc], oacc[fr][fc], 0, 0, 0); \
    }                                                                          \
    __builtin_amdgcn_s_setprio(0);                                             \
  }

  // pv0: V0 must be in (vmcnt(4): V1 stays in flight)
  EXPWRITE(0)
  asm volatile("s_waitcnt lgkmcnt(0)" ::: "memory");
  asm volatile("s_waitcnt vmcnt(4)" ::: "memory");
  __builtin_amdgcn_s_barrier();
  asm volatile("" ::: "memory");
  PVMFMA(0)
  __builtin_amdgcn_s_barrier();
  asm volatile("" ::: "memory");
  IVC(2, 0)
  // pv1
  EXPWRITE(1)
  asm volatile("s_waitcnt lgkmcnt(0)" ::: "memory");
  asm volatile("s_waitcnt vmcnt(4)" ::: "memory");
  __builtin_amdgcn_s_barrier();
  asm volatile("" ::: "memory");
  PVMFMA(1)
  __builtin_amdgcn_s_barrier();
  asm volatile("" ::: "memory");
  IVC(3, 1)
  // pv2
  EXPWRITE(2)
  asm volatile("s_waitcnt lgkmcnt(0)" ::: "memory");
  asm volatile("s_waitcnt vmcnt(4)" ::: "memory");
  __builtin_amdgcn_s_barrier();
  asm volatile("" ::: "memory");
  PVMFMA(2)
  __builtin_amdgcn_s_barrier();
  asm volatile("" ::: "memory");
  // pv3
  EXPWRITE(3)
  asm volatile("s_waitcnt lgkmcnt(0)" ::: "memory");
  asm volatile("s_waitcnt vmcnt(0)" ::: "memory");
  __builtin_amdgcn_s_barrier();
  asm volatile("" ::: "memory");
  PVMFMA(3)
#undef IVC
#undef EXPWRITE
#undef PVMFMA

  // ---- row sums -> reds; epilogue ----
#pragma unroll
  for (int fr = 0; fr < 4; ++fr)
#pragma unroll
    for (int i = 0; i < 4; ++i) {
      float s = s4[fr][i];
      s += __shfl_xor(s, 1);
      s += __shfl_xor(s, 2);
      s += __shfl_xor(s, 4);
      s += __shfl_xor(s, 8);
      if (lr == 0) reds[wn * 128 + wm * 64 + fr * 16 + lq * 4 + i] = s;
    }
  asm volatile("s_waitcnt lgkmcnt(0)" ::: "memory");
  __builtin_amdgcn_s_barrier();
  asm volatile("" ::: "memory");

#pragma unroll
  for (int fr = 0; fr < 4; ++fr)
#pragma unroll
    for (int i = 0; i < 4; ++i) {
      const int row = wm * 64 + fr * 16 + lq * 4 + i;
      const float rs = (reds[row] + reds[128 + row]) + (reds[256 + row] + reds[384 + row]);
#pragma unroll
      for (int fc = 0; fc < 2; ++fc) {
        const int col = wn * 32 + fc * 16 + lr;
        Og[((size_t)b * 512 + q0 + row) * 1024 + h * 128 + col] =
            __float2bfloat16(oacc[fr][fc][i] / rs);
      }
    }
}

extern "C" void kernel_launch(void* const* d_in, const int* in_sizes, int n_in,
                              void* d_out, int out_size, void* d_ws, size_t ws_size,
                              hipStream_t stream) {
  (void)in_sizes; (void)n_in; (void)out_size; (void)ws_size;
  const float* x  = (const float*)d_in[0];
  const float* Wq = (const float*)d_in[1];
  const float* bq = (const float*)d_in[2];
  const float* Wk = (const float*)d_in[3];
  const float* bk = (const float*)d_in[4];
  const float* Wv = (const float*)d_in[5];
  const float* bv = (const float*)d_in[6];
  const float* W1 = (const float*)d_in[7];
  const float* b1 = (const float*)d_in[8];
  const float* W2 = (const float*)d_in[9];
  const float* b2 = (const float*)d_in[10];
  float* out = (float*)d_out;
  char* ws = (char*)d_ws;
  constexpr size_t MB = 1ull << 20;

  bf16* XB  = (bf16*)(ws + 0);
  bf16* WQT = (bf16*)(ws + 32 * MB);
  bf16* WKT = (bf16*)(ws + 34 * MB);
  bf16* WVT = (bf16*)(ws + 36 * MB);
  bf16* W1T = (bf16*)(ws + 38 * MB);
  bf16* W2T = (bf16*)(ws + 54 * MB);
  bf16* OB  = (bf16*)(ws + 70 * MB);
  bf16* QB  = (bf16*)(ws + 102 * MB);
  bf16* KB  = (bf16*)(ws + 134 * MB);
  bf16* VB  = (bf16*)(ws + 166 * MB);
  bf16* VT  = (bf16*)(ws + 0);        // overlays dead XB after QKV
  bf16* HC  = (bf16*)(ws + 102 * MB); // overlays dead QB/KB after attn

  k_cvt_bf16<<<2048, 256, 0, stream>>>(x, XB, (16384 * 1024) / 4);
  k_transpose_w<<<dim3(32, 32), 256, 0, stream>>>(Wq, WQT, 1024, 1024);
  k_transpose_w<<<dim3(32, 32), 256, 0, stream>>>(Wk, WKT, 1024, 1024);
  k_transpose_w<<<dim3(32, 32), 256, 0, stream>>>(Wv, WVT, 1024, 1024);
  k_transpose_w<<<dim3(256, 32), 256, 0, stream>>>(W1, W1T, 1024, 8192);
  k_transpose_w<<<dim3(32, 256), 256, 0, stream>>>(W2, W2T, 8192, 1024);

  // QKV projections (M=16384, N=1024, K=1024): grid (4, 64) = 256 wgs
  k_gemm256<0, false><<<dim3(4, 64), 512, 0, stream>>>(XB, WQT, bq, QB, 1024, 1024, 1024, 1024);
  k_gemm256<0, false><<<dim3(4, 64), 512, 0, stream>>>(XB, WKT, bk, KB, 1024, 1024, 1024, 1024);
  k_gemm256<0, false><<<dim3(4, 64), 512, 0, stream>>>(XB, WVT, bv, VB, 1024, 1024, 1024, 1024);

  k_transpose_v<<<dim3(16, 4, 256), 256, 0, stream>>>(VB, VT);
  k_attn<<<1024, 512, 0, stream>>>(QB, KB, VT, OB);

  // FFN chunked over F (4 x 2048)
  for (int chk = 0; chk < 4; ++chk) {
    k_gemm256<1, false><<<dim3(8, 64), 512, 0, stream>>>(
        OB, W1T + (size_t)chk * 2048 * 1024, b1 + chk * 2048, HC, 1024, 1024, 1024, 2048);
    if (chk == 0)
      k_gemm256<2, false><<<dim3(4, 64), 512, 0, stream>>>(
          HC, W2T + chk * 2048, b2, out, 2048, 2048, 8192, 1024);
    else
      k_gemm256<2, true><<<dim3(4, 64), 512, 0, stream>>>(
          HC, W2T + chk * 2048, nullptr, out, 2048, 2048, 8192, 1024);
  }
}

// Round 9
// 977.352 us; speedup vs baseline: 1.1450x; 1.0099x over previous
//
#include <hip/hip_runtime.h>
#include <hip/hip_bf16.h>
#include <math.h>

typedef __attribute__((ext_vector_type(8))) short bf16x8;
typedef __attribute__((ext_vector_type(4))) float f32x4;
typedef __hip_bfloat16 bf16;

__device__ __forceinline__ void gload_lds16(const void* g, void* l) {
  __builtin_amdgcn_global_load_lds((const __attribute__((address_space(1))) void*)g,
                                   (__attribute__((address_space(3))) void*)l,
                                   16, 0, 0);
}

__device__ __forceinline__ float gelu_erf(float x) {
  return 0.5f * x * (1.0f + erff(x * 0.70710678118654752f));
}

// ---------------- convert f32 -> bf16 (vectorized) ----------------
__global__ __launch_bounds__(256) void k_cvt_bf16(const float* __restrict__ in,
                                                  bf16* __restrict__ out, int n4) {
  int i = blockIdx.x * 256 + threadIdx.x;
  const int stride = gridDim.x * 256;
  for (; i < n4; i += stride) {
    float4 v = reinterpret_cast<const float4*>(in)[i];
    bf16* o = out + (size_t)i * 4;
    o[0] = __float2bfloat16(v.x);
    o[1] = __float2bfloat16(v.y);
    o[2] = __float2bfloat16(v.z);
    o[3] = __float2bfloat16(v.w);
  }
}

// ---------------- transpose f32 [R][C] -> bf16 [C][R] ----------------
__global__ __launch_bounds__(256) void k_transpose_w(const float* __restrict__ in,
                                                     bf16* __restrict__ out,
                                                     int R, int C) {
  __shared__ float tile[32][33];
  const int c0 = blockIdx.x * 32, r0 = blockIdx.y * 32;
  const int tx = threadIdx.x & 31, ty = threadIdx.x >> 5;
  for (int i = 0; i < 32; i += 8)
    tile[ty + i][tx] = in[(size_t)(r0 + ty + i) * C + c0 + tx];
  __syncthreads();
  for (int i = 0; i < 32; i += 8)
    out[(size_t)(c0 + ty + i) * R + r0 + tx] = __float2bfloat16(tile[tx][ty + i]);
}

// ------------- per-head V transpose: [B*S][E] -> [(b*H+h)*128 + d][S] -------------
__global__ __launch_bounds__(256) void k_transpose_v(const bf16* __restrict__ Vb,
                                                     bf16* __restrict__ Vt) {
  __shared__ bf16 tile[32][34];
  const int bh = blockIdx.z;
  const int b = bh >> 3, h = bh & 7;
  const int s0 = blockIdx.x * 32, d0 = blockIdx.y * 32;
  const int tx = threadIdx.x & 31, ty = threadIdx.x >> 5;
  for (int i = 0; i < 32; i += 8)
    tile[ty + i][tx] = Vb[((size_t)b * 512 + s0 + ty + i) * 1024 + h * 128 + d0 + tx];
  __syncthreads();
  for (int i = 0; i < 32; i += 8)
    Vt[((size_t)bh * 128 + d0 + ty + i) * 512 + s0 + tx] = tile[tx][ty + i];
}

// ======== 256x256, BK=64, 8-wave GEMM: 4-phase + COUNTED vmcnt (T3+T4) ========
// C = A * Bt^T + bias. EPI: 0=bf16, 1=gelu->bf16, 2=f32(+=ACC).
// LDS 128KB = 2 slots x (A 32KB + B 32KB). Quadrant-aligned half-tiles via row
// permutation: A LDS rows 0-127 = global rows {wm*128+0..63} (fr0-3 for both wm);
// B LDS rows 0-127 = global rows {wn*64+0..31} (fc0-1 for all wn). Each quadrant
// needs exactly one A-half + one B-half. Issue order/tile: A0,B0,B1,A1 (1/phase);
// waits vmcnt(4) (2 issues always in flight; tail 4/2/0). Swizzle 16B-slot ^=
// (LDSrow&7), inverse-applied on global source (gload_lds dest linear).
template <int EPI, bool ACC>
__global__ __launch_bounds__(512, 2) void k_gemm256(
    const bf16* __restrict__ A, const bf16* __restrict__ Bt,
    const float* __restrict__ bias, void* __restrict__ Cout,
    int K, int lda, int ldb, int ldc) {
  __shared__ __attribute__((aligned(16))) char lds[131072];
  const int t = threadIdx.x, w = t >> 6, l = t & 63;
  const int gx = gridDim.x, nwg = gx * gridDim.y;
  int bid = blockIdx.y * gx + blockIdx.x;
  bid = (bid & 7) * (nwg >> 3) + (bid >> 3);  // XCD swizzle (nwg % 8 == 0)
  const int bm = bid / gx, bn = bid % gx;
  const int wm = w >> 2, wn = w & 3;
  const int lq = l >> 4, lr = l & 15;

  // ---- staging pointers: thread covers LDS segs t and t+512 of each half ----
  const char* Ab = (const char*)(A + (size_t)(bm * 256) * lda);
  const char* Bb = (const char*)(Bt + (size_t)(bn * 256) * ldb);
  const int r0 = t >> 3, s0x = ((t & 7) ^ (r0 & 7)) << 4;          // LDS row, swz src slot
  const int r1 = (t + 512) >> 3, s1x = (((t + 512) & 7) ^ (r1 & 7)) << 4;
  const size_t la = (size_t)lda * 2, lb = (size_t)ldb * 2;
  // A half k: global row = (r>>6)*128 + k*64 + (r&63); B half k: (r>>5)*64 + k*32 + (r&31)
  const char* pA00 = Ab + (size_t)((r0 >> 6) * 128 + (r0 & 63)) * la + s0x;
  const char* pA10 = Ab + (size_t)((r1 >> 6) * 128 + (r1 & 63)) * la + s1x;
  const char* pA01 = Ab + (size_t)((r0 >> 6) * 128 + 64 + (r0 & 63)) * la + s0x;
  const char* pA11 = Ab + (size_t)((r1 >> 6) * 128 + 64 + (r1 & 63)) * la + s1x;
  const char* pB00 = Bb + (size_t)((r0 >> 5) * 64 + (r0 & 31)) * lb + s0x;
  const char* pB10 = Bb + (size_t)((r1 >> 5) * 64 + (r1 & 31)) * lb + s1x;
  const char* pB01 = Bb + (size_t)((r0 >> 5) * 64 + 32 + (r0 & 31)) * lb + s0x;
  const char* pB11 = Bb + (size_t)((r1 >> 5) * 64 + 32 + (r1 & 31)) * lb + s1x;

  // ---- fragment read offsets (permuted rows; swz key = LDS row&7 = lr&7) ----
  const int swzb = (lq ^ (lr & 7)) << 4;            // ^ (kk<<6) for kk=1
  const int aoff = wm * 8192 + lr * 128;            // + half*16384 + (fr&3)*2048
  const int boff = 32768 + wn * 4096 + lr * 128;    // + half*16384 + (fc&1)*2048

  f32x4 acc[8][4];
#pragma unroll
  for (int m = 0; m < 8; ++m)
#pragma unroll
    for (int n = 0; n < 4; ++n) acc[m][n] = (f32x4){0.f, 0.f, 0.f, 0.f};

#define ISSUE_A0(S) { gload_lds16(pA00, (S) + w * 1024); gload_lds16(pA10, (S) + 8192 + w * 1024); pA00 += 128; pA10 += 128; }
#define ISSUE_A1(S) { gload_lds16(pA01, (S) + 16384 + w * 1024); gload_lds16(pA11, (S) + 16384 + 8192 + w * 1024); pA01 += 128; pA11 += 128; }
#define ISSUE_B0(S) { gload_lds16(pB00, (S) + 32768 + w * 1024); gload_lds16(pB10, (S) + 32768 + 8192 + w * 1024); pB00 += 128; pB10 += 128; }
#define ISSUE_B1(S) { gload_lds16(pB01, (S) + 49152 + w * 1024); gload_lds16(pB11, (S) + 49152 + 8192 + w * 1024); pB01 += 128; pB11 += 128; }

  bf16x8 aF[4][2], bF01[2][2], bF23[2][2];
#define READ_A03(C) { _Pragma("unroll") for (int fr = 0; fr < 4; ++fr) _Pragma("unroll") for (int kk = 0; kk < 2; ++kk) aF[fr][kk] = *(const bf16x8*)((C) + aoff + fr * 2048 + (swzb ^ (kk << 6))); }
#define READ_A47(C) { _Pragma("unroll") for (int fr = 0; fr < 4; ++fr) _Pragma("unroll") for (int kk = 0; kk < 2; ++kk) aF[fr][kk] = *(const bf16x8*)((C) + 16384 + aoff + fr * 2048 + (swzb ^ (kk << 6))); }
#define READ_B01(C) { _Pragma("unroll") for (int fc = 0; fc < 2; ++fc) _Pragma("unroll") for (int kk = 0; kk < 2; ++kk) bF01[fc][kk] = *(const bf16x8*)((C) + boff + fc * 2048 + (swzb ^ (kk << 6))); }
#define READ_B23(C) { _Pragma("unroll") for (int fc = 0; fc < 2; ++fc) _Pragma("unroll") for (int kk = 0; kk < 2; ++kk) bF23[fc][kk] = *(const bf16x8*)((C) + 16384 + boff + fc * 2048 + (swzb ^ (kk << 6))); }

#define MFMA_Q(ACCR, BFR)                                               \
  { __builtin_amdgcn_s_setprio(1);                                      \
    _Pragma("unroll") for (int fr = 0; fr < 4; ++fr)                    \
      _Pragma("unroll") for (int fc = 0; fc < 2; ++fc)                  \
        _Pragma("unroll") for (int kk = 0; kk < 2; ++kk)                \
          acc[ACCR + fr][fc + ((&BFR == &bF23) ? 2 : 0)] =              \
              __builtin_amdgcn_mfma_f32_16x16x32_bf16(aF[fr][kk], BFR[fc][kk], acc[ACCR + fr][fc + ((&BFR == &bF23) ? 2 : 0)], 0, 0, 0); \
    __builtin_amdgcn_s_setprio(0); }

  // prologue: tile 0 fully issued into slot 0
  ISSUE_A0(lds); ISSUE_B0(lds); ISSUE_B1(lds); ISSUE_A1(lds);

  const int NT = K >> 6;
  for (int kt = 0; kt < NT; ++kt) {
    char* cur = lds + (kt & 1) * 65536;
    char* nxt = lds + ((kt & 1) ^ 1) * 65536;
    const bool pre = (kt + 1 < NT);

    // ---- ph1: wait A0,B0(kt); read; issue A0(kt+1); MFMA Q(fr0-3,fc0-1)
    asm volatile("s_waitcnt vmcnt(4)" ::: "memory");
    __builtin_amdgcn_s_barrier();
    READ_A03(cur); READ_B01(cur);
    if (pre) ISSUE_A0(nxt);
    __builtin_amdgcn_s_barrier();
    MFMA_Q(0, bF01)
    if (pre) { asm volatile("s_waitcnt vmcnt(4)" ::: "memory"); }
    else     { asm volatile("s_waitcnt vmcnt(2)" ::: "memory"); }
    __builtin_amdgcn_s_barrier();

    // ---- ph2: read B23 (B1(kt) landed); issue B0(kt+1); MFMA Q(fr0-3,fc2-3)
    READ_B23(cur);
    if (pre) ISSUE_B0(nxt);
    __builtin_amdgcn_s_barrier();
    MFMA_Q(0, bF23)
    if (pre) { asm volatile("s_waitcnt vmcnt(4)" ::: "memory"); }
    else     { asm volatile("s_waitcnt vmcnt(0)" ::: "memory"); }
    __builtin_amdgcn_s_barrier();

    // ---- ph3: read A47 (A1(kt) landed); issue B1(kt+1); MFMA Q(fr4-7,fc0-1)
    READ_A47(cur);
    if (pre) ISSUE_B1(nxt);
    __builtin_amdgcn_s_barrier();
    MFMA_Q(4, bF01)
    __builtin_amdgcn_s_barrier();

    // ---- ph4: issue A1(kt+1); MFMA Q(fr4-7,fc2-3); loop-top does vmcnt+barrier
    if (pre) ISSUE_A1(nxt);
    MFMA_Q(4, bF23)
  }
#undef ISSUE_A0
#undef ISSUE_A1
#undef ISSUE_B0
#undef ISSUE_B1
#undef READ_A03
#undef READ_A47
#undef READ_B01
#undef READ_B23
#undef MFMA_Q

  // ---- epilogue ----
  const int rowb = bm * 256 + wm * 128;
  const int colb = bn * 256 + wn * 64;
#pragma unroll
  for (int fr = 0; fr < 8; ++fr) {
#pragma unroll
    for (int fc = 0; fc < 4; ++fc) {
      const int col = colb + fc * 16 + lr;
      const float bv = bias ? bias[col] : 0.0f;
#pragma unroll
      for (int i = 0; i < 4; ++i) {
        const int row = rowb + fr * 16 + lq * 4 + i;
        float v = acc[fr][fc][i] + bv;
        if (EPI == 1) v = gelu_erf(v);
        if (EPI <= 1) {
          ((bf16*)Cout)[(size_t)row * ldc + col] = __float2bfloat16(v);
        } else {
          float* Cf = (float*)Cout;
          const size_t idx = (size_t)row * ldc + col;
          if (ACC) v += Cf[idx];
          Cf[idx] = v;
        }
      }
    }
  }
}

// ======== attention v5: GEMM-style, K fully LDS-resident (unchanged, 132us) ========
__global__ __launch_bounds__(512, 1) void k_attn(const bf16* __restrict__ Qg,
                                                 const bf16* __restrict__ Kg,
                                                 const bf16* __restrict__ Vt,
                                                 bf16* __restrict__ Og) {
  __shared__ __attribute__((aligned(16))) char lds[131072];
  int bid = blockIdx.x;
  bid = (bid & 7) * 128 + (bid >> 3);  // XCD swizzle, 1024 = 8*128
  const int bh = bid >> 2, q0 = (bid & 3) * 128;
  const int b = bh >> 3, h = bh & 7;
  const int t = threadIdx.x, w = t >> 6, l = t & 63;
  const int lq = l >> 4, lr = l & 15;
  const int wm = w >> 2, wn = w & 3;

  const int sr = t >> 4;
  const int ss = (t & 15) ^ (sr & 15);
  {
    const bf16* ks = Kg + ((size_t)b * 512 + sr) * 1024 + h * 128 + ss * 8;
#pragma unroll
    for (int j = 0; j < 16; ++j)
      gload_lds16(ks + (size_t)j * 32 * 1024, lds + j * 8192 + w * 1024);
  }

  bf16x8 qf[4][4];
  {
    const bf16* qb = Qg + ((size_t)b * 512 + q0 + wm * 64 + lr) * 1024 + h * 128 + lq * 8;
#pragma unroll
    for (int fr = 0; fr < 4; ++fr)
#pragma unroll
      for (int d0 = 0; d0 < 4; ++d0)
        qf[fr][d0] = *(const bf16x8*)(qb + (size_t)(fr * 16) * 1024 + d0 * 32);
  }

  asm volatile("s_waitcnt vmcnt(0)" ::: "memory");
  __builtin_amdgcn_s_barrier();
  asm volatile("" ::: "memory");

  f32x4 accS[4][8];
#pragma unroll
  for (int fr = 0; fr < 4; ++fr)
#pragma unroll
    for (int fc = 0; fc < 8; ++fc) accS[fr][fc] = (f32x4){0.f, 0.f, 0.f, 0.f};

  __builtin_amdgcn_s_setprio(1);
#pragma unroll
  for (int fc = 0; fc < 8; ++fc) {
    bf16x8 kf[4];
#pragma unroll
    for (int d0 = 0; d0 < 4; ++d0)
      kf[d0] = *(const bf16x8*)(lds + (wn * 128 + fc * 16 + lr) * 256 +
                                (((d0 * 4 + lq) ^ lr) << 4));
#pragma unroll
    for (int d0 = 0; d0 < 4; ++d0)
#pragma unroll
      for (int fr = 0; fr < 4; ++fr)
        accS[fr][fc] = __builtin_amdgcn_mfma_f32_16x16x32_bf16(qf[fr][d0], kf[d0], accS[fr][fc], 0, 0, 0);
  }
  __builtin_amdgcn_s_setprio(0);

  __builtin_amdgcn_s_barrier();
  asm volatile("" ::: "memory");

  const bf16* vs = Vt + ((size_t)bh * 128 + sr) * 512 + ss * 8;
#define IVC(kc, slot)                                                         \
  {                                                                           \
    _Pragma("unroll") for (int j = 0; j < 4; ++j)                             \
        gload_lds16(vs + (size_t)j * 32 * 512 + (kc) * 128,                   \
                    lds + (slot) * 32768 + j * 8192 + w * 1024);              \
  }
  IVC(0, 0)
  IVC(1, 1)

  float* redm = (float*)(lds + 98304);
  float* reds = (float*)(lds + 100352);
  float fm[4][4];
#pragma unroll
  for (int fr = 0; fr < 4; ++fr)
#pragma unroll
    for (int i = 0; i < 4; ++i) {
      float m = accS[fr][0][i];
#pragma unroll
      for (int fc = 1; fc < 8; ++fc) m = fmaxf(m, accS[fr][fc][i]);
      m = fmaxf(m, __shfl_xor(m, 1));
      m = fmaxf(m, __shfl_xor(m, 2));
      m = fmaxf(m, __shfl_xor(m, 4));
      m = fmaxf(m, __shfl_xor(m, 8));
      if (lr == 0) redm[wn * 128 + wm * 64 + fr * 16 + lq * 4 + i] = m;
    }
  asm volatile("s_waitcnt lgkmcnt(0)" ::: "memory");
  __builtin_amdgcn_s_barrier();
  asm volatile("" ::: "memory");
#pragma unroll
  for (int fr = 0; fr < 4; ++fr)
#pragma unroll
    for (int i = 0; i < 4; ++i) {
      const int row = wm * 64 + fr * 16 + lq * 4 + i;
      fm[fr][i] = fmaxf(fmaxf(redm[row], redm[128 + row]),
                        fmaxf(redm[256 + row], redm[384 + row]));
    }

  f32x4 oacc[4][2];
#pragma unroll
  for (int fr = 0; fr < 4; ++fr)
#pragma unroll
    for (int fc = 0; fc < 2; ++fc) oacc[fr][fc] = (f32x4){0.f, 0.f, 0.f, 0.f};
  float s4[4][4];
#pragma unroll
  for (int fr = 0; fr < 4; ++fr)
#pragma unroll
    for (int i = 0; i < 4; ++i) s4[fr][i] = 0.f;

#define EXPWRITE(kc)                                                           \
  if (wn == (kc)) {                                                            \
    _Pragma("unroll") for (int fr = 0; fr < 4; ++fr)                           \
      _Pragma("unroll") for (int i = 0; i < 4; ++i) {                          \
        const int row = wm * 64 + fr * 16 + lq * 4 + i;                        \
        const int rx = lq * 4 + i;                                             \
        _Pragma("unroll") for (int fc = 0; fc < 8; ++fc) {                     \
          const float e = __expf(accS[fr][fc][i] - fm[fr][i]);                 \
          s4[fr][i] += e;                                                      \
          *(unsigned short*)(lds + 65536 + row * 256 +                         \
                             (((fc * 2 + (lr >> 3)) ^ rx) << 4) + (lr & 7) * 2) = \
              __bfloat16_as_ushort(__float2bfloat16(e));                       \
        }                                                                      \
      }                                                                        \
  }

#define PVMFMA(kc)                                                             \
  {                                                                            \
    const char* Vb = lds + ((kc) & 1) * 32768;                                 \
    __builtin_amdgcn_s_setprio(1);                                             \
    _Pragma("unroll") for (int kk = 0; kk < 4; ++kk) {                         \
      bf16x8 pa[4], vb[2];                                                     \
      _Pragma("unroll") for (int fr = 0; fr < 4; ++fr)                         \
          pa[fr] = *(const bf16x8*)(lds + 65536 + (wm * 64 + fr * 16 + lr) * 256 + \
                                    (((kk * 4 + lq) ^ lr) << 4));              \
      _Pragma("unroll") for (int fc = 0; fc < 2; ++fc)                         \
          vb[fc] = *(const bf16x8*)(Vb + (wn * 32 + fc * 16 + lr) * 256 +      \
                                    (((kk * 4 + lq) ^ lr) << 4));              \
      _Pragma("unroll") for (int fr = 0; fr < 4; ++fr)                         \
        _Pragma("unroll") for (int fc = 0; fc < 2; ++fc)                       \
          oacc[fr][fc] = __builtin_amdgcn_mfma_f32_16x16x32_bf16(pa[fr], vb[fc], oacc[fr][fc], 0, 0, 0); \
    }                                                                          \
    __builtin_amdgcn_s_setprio(0);                                             \
  }

  EXPWRITE(0)
  asm volatile("s_waitcnt lgkmcnt(0)" ::: "memory");
  asm volatile("s_waitcnt vmcnt(4)" ::: "memory");
  __builtin_amdgcn_s_barrier();
  asm volatile("" ::: "memory");
  PVMFMA(0)
  __builtin_amdgcn_s_barrier();
  asm volatile("" ::: "memory");
  IVC(2, 0)
  EXPWRITE(1)
  asm volatile("s_waitcnt lgkmcnt(0)" ::: "memory");
  asm volatile("s_waitcnt vmcnt(4)" ::: "memory");
  __builtin_amdgcn_s_barrier();
  asm volatile("" ::: "memory");
  PVMFMA(1)
  __builtin_amdgcn_s_barrier();
  asm volatile("" ::: "memory");
  IVC(3, 1)
  EXPWRITE(2)
  asm volatile("s_waitcnt lgkmcnt(0)" ::: "memory");
  asm volatile("s_waitcnt vmcnt(4)" ::: "memory");
  __builtin_amdgcn_s_barrier();
  asm volatile("" ::: "memory");
  PVMFMA(2)
  __builtin_amdgcn_s_barrier();
  asm volatile("" ::: "memory");
  EXPWRITE(3)
  asm volatile("s_waitcnt lgkmcnt(0)" ::: "memory");
  asm volatile("s_waitcnt vmcnt(0)" ::: "memory");
  __builtin_amdgcn_s_barrier();
  asm volatile("" ::: "memory");
  PVMFMA(3)
#undef IVC
#undef EXPWRITE
#undef PVMFMA

#pragma unroll
  for (int fr = 0; fr < 4; ++fr)
#pragma unroll
    for (int i = 0; i < 4; ++i) {
      float s = s4[fr][i];
      s += __shfl_xor(s, 1);
      s += __shfl_xor(s, 2);
      s += __shfl_xor(s, 4);
      s += __shfl_xor(s, 8);
      if (lr == 0) reds[wn * 128 + wm * 64 + fr * 16 + lq * 4 + i] = s;
    }
  asm volatile("s_waitcnt lgkmcnt(0)" ::: "memory");
  __builtin_amdgcn_s_barrier();
  asm volatile("" ::: "memory");

#pragma unroll
  for (int fr = 0; fr < 4; ++fr)
#pragma unroll
    for (int i = 0; i < 4; ++i) {
      const int row = wm * 64 + fr * 16 + lq * 4 + i;
      const float rs = (reds[row] + reds[128 + row]) + (reds[256 + row] + reds[384 + row]);
#pragma unroll
      for (int fc = 0; fc < 2; ++fc) {
        const int col = wn * 32 + fc * 16 + lr;
        Og[((size_t)b * 512 + q0 + row) * 1024 + h * 128 + col] =
            __float2bfloat16(oacc[fr][fc][i] / rs);
      }
    }
}

extern "C" void kernel_launch(void* const* d_in, const int* in_sizes, int n_in,
                              void* d_out, int out_size, void* d_ws, size_t ws_size,
                              hipStream_t stream) {
  (void)in_sizes; (void)n_in; (void)out_size; (void)ws_size;
  const float* x  = (const float*)d_in[0];
  const float* Wq = (const float*)d_in[1];
  const float* bq = (const float*)d_in[2];
  const float* Wk = (const float*)d_in[3];
  const float* bk = (const float*)d_in[4];
  const float* Wv = (const float*)d_in[5];
  const float* bv = (const float*)d_in[6];
  const float* W1 = (const float*)d_in[7];
  const float* b1 = (const float*)d_in[8];
  const float* W2 = (const float*)d_in[9];
  const float* b2 = (const float*)d_in[10];
  float* out = (float*)d_out;
  char* ws = (char*)d_ws;
  constexpr size_t MB = 1ull << 20;

  bf16* XB  = (bf16*)(ws + 0);
  bf16* WQT = (bf16*)(ws + 32 * MB);
  bf16* WKT = (bf16*)(ws + 34 * MB);
  bf16* WVT = (bf16*)(ws + 36 * MB);
  bf16* W1T = (bf16*)(ws + 38 * MB);
  bf16* W2T = (bf16*)(ws + 54 * MB);
  bf16* OB  = (bf16*)(ws + 70 * MB);
  bf16* QB  = (bf16*)(ws + 102 * MB);
  bf16* KB  = (bf16*)(ws + 134 * MB);
  bf16* VB  = (bf16*)(ws + 166 * MB);
  bf16* VT  = (bf16*)(ws + 0);        // overlays dead XB after QKV
  bf16* HC  = (bf16*)(ws + 102 * MB); // overlays dead QB/KB after attn

  k_cvt_bf16<<<2048, 256, 0, stream>>>(x, XB, (16384 * 1024) / 4);
  k_transpose_w<<<dim3(32, 32), 256, 0, stream>>>(Wq, WQT, 1024, 1024);
  k_transpose_w<<<dim3(32, 32), 256, 0, stream>>>(Wk, WKT, 1024, 1024);
  k_transpose_w<<<dim3(32, 32), 256, 0, stream>>>(Wv, WVT, 1024, 1024);
  k_transpose_w<<<dim3(256, 32), 256, 0, stream>>>(W1, W1T, 1024, 8192);
  k_transpose_w<<<dim3(32, 256), 256, 0, stream>>>(W2, W2T, 8192, 1024);

  // QKV projections (M=16384, N=1024, K=1024): grid (4, 64) = 256 wgs
  k_gemm256<0, false><<<dim3(4, 64), 512, 0, stream>>>(XB, WQT, bq, QB, 1024, 1024, 1024, 1024);
  k_gemm256<0, false><<<dim3(4, 64), 512, 0, stream>>>(XB, WKT, bk, KB, 1024, 1024, 1024, 1024);
  k_gemm256<0, false><<<dim3(4, 64), 512, 0, stream>>>(XB, WVT, bv, VB, 1024, 1024, 1024, 1024);

  k_transpose_v<<<dim3(16, 4, 256), 256, 0, stream>>>(VB, VT);
  k_attn<<<1024, 512, 0, stream>>>(QB, KB, VT, OB);

  // FFN chunked over F (4 x 2048)
  for (int chk = 0; chk < 4; ++chk) {
    k_gemm256<1, false><<<dim3(8, 64), 512, 0, stream>>>(
        OB, W1T + (size_t)chk * 2048 * 1024, b1 + chk * 2048, HC, 1024, 1024, 1024, 2048);
    if (chk == 0)
      k_gemm256<2, false><<<dim3(4, 64), 512, 0, stream>>>(
          HC, W2T + chk * 2048, b2, out, 2048, 2048, 8192, 1024);
    else
      k_gemm256<2, true><<<dim3(4, 64), 512, 0, stream>>>(
          HC, W2T + chk * 2048, nullptr, out, 2048, 2048, 8192, 1024);
  }
}